// Round 6
// baseline (13769.711 us; speedup 1.0000x reference)
//
#include <hip/hip_runtime.h>
#include <math.h>

// RITS recurrent imputation. B=256, T=100, F=256, H=512.
// Round 6: ZERO grid sync. The entire recurrence is row-local in batch:
// 16 persistent wgs (512 thr, 8 waves), each owns 16 batch rows for all T
// steps; h/c/hdec/cc live in LDS; weights stream from L2. Only cross-wg op
// is one atomicAdd (loss) at the end. No cross-XCD coherence assumptions.
//   per step: stage m -> phase A (x_h) -> phase B (z_h/c_c) -> phase C
//   (gates K=1024 [cc|m|hdec] + fused LSTM), 3 __syncthreads/step.

#define T_ 100
typedef unsigned short ushortT;
typedef __attribute__((ext_vector_type(8))) short short8;
typedef __attribute__((ext_vector_type(4))) float f32x4;

// ---- workspace byte offsets ----
#define OB_DEN   0u          // f32 [128] mask sums per t
#define OB_BIASP 512u        // f32 [2048] packed b_ih+b_hh
#define OB_BA    8704u       // bf16 W_hist [256,512]
#define OB_BF    270848u     // bf16 W_feat masked [256,256]
#define OB_BC    401920u     // bf16 packed [2048,1024] = [Wih|Whh], row n=4j+g
#define OB_BTH   4596224u    // bf16 W_td_h [512,256]
#define OB_BCB   4858368u    // bf16 W_comb [256,512]
#define OB_GXM   5120512u    // bf16 [25600,512] = [gamma_x | m] (b-major rows)
#define OB_DT    31334912u   // bf16 deltas [25600,256] (b-major rows)
#define OB_GHT   44442112u   // bf16 gamma_h TIME-major [100,256,512]
#define OB_ALT   70656512u   // bf16 alpha  TIME-major [100,256,256]
// end 83,763,712 B (~79.9 MB, within known-good ws)

__device__ __forceinline__ float sigm(float x) { return 1.0f / (1.0f + expf(-x)); }

__device__ __forceinline__ ushortT f2bf(float f) {
    union { float f; unsigned u; } v; v.f = f;
    unsigned r = v.u + 0x7fffu + ((v.u >> 16) & 1u);   // RNE
    return (ushortT)(r >> 16);
}
__device__ __forceinline__ float bf2f(ushortT h) {
    union { unsigned u; float f; } v; v.u = ((unsigned)h) << 16; return v.f;
}

// ---------------- prep ----------------

__global__ __launch_bounds__(256) void k_prepw(const float* __restrict__ W_ih,
                                               const float* __restrict__ W_hh,
                                               const float* __restrict__ b_ih,
                                               const float* __restrict__ b_hh,
                                               const float* __restrict__ W_hist,
                                               const float* __restrict__ W_feat,
                                               const float* __restrict__ W_comb,
                                               const float* __restrict__ W_td_h,
                                               unsigned char* wsb) {
    ushortT* Bc  = (ushortT*)(wsb + OB_BC);
    ushortT* Ba  = (ushortT*)(wsb + OB_BA);
    ushortT* Bf  = (ushortT*)(wsb + OB_BF);
    ushortT* Bcb = (ushortT*)(wsb + OB_BCB);
    ushortT* Bth = (ushortT*)(wsb + OB_BTH);
    float* biasp = (float*)(wsb + OB_BIASP);
    int n = blockIdx.x, j = n >> 2, g = n & 3, src = g * 512 + j;
    for (int k = threadIdx.x; k < 512; k += 256) {
        Bc[(size_t)n * 1024 + k]       = f2bf(W_ih[(size_t)src * 512 + k]);
        Bc[(size_t)n * 1024 + 512 + k] = f2bf(W_hh[(size_t)src * 512 + k]);
        if (n < 256) {
            Ba[(size_t)n * 512 + k]  = f2bf(W_hist[(size_t)n * 512 + k]);
            Bcb[(size_t)n * 512 + k] = f2bf(W_comb[(size_t)n * 512 + k]);
            if (k < 256) Bf[n * 256 + k] = (k == n) ? (ushortT)0 : f2bf(W_feat[n * 256 + k]);
        }
        if (n < 512 && k < 256) Bth[n * 256 + k] = f2bf(W_td_h[n * 256 + k]);
    }
    if (threadIdx.x == 0) biasp[n] = b_ih[src] + b_hh[src];
}

__global__ __launch_bounds__(256) void k_den(const float* __restrict__ masks,
                                             unsigned char* wsb) {
    __shared__ float red[256];
    float* den = (float*)(wsb + OB_DEN);
    int t = blockIdx.x;
    float s = 0.0f;
    for (int idx = threadIdx.x; idx < 256 * 256; idx += 256) {
        int b = idx >> 8, f = idx & 255;
        s += masks[((size_t)b * T_ + t) * 256 + f];
    }
    red[threadIdx.x] = s; __syncthreads();
    for (int st = 128; st > 0; st >>= 1) {
        if (threadIdx.x < st) red[threadIdx.x] += red[threadIdx.x + st];
        __syncthreads();
    }
    if (threadIdx.x == 0) den[t] = red[0];
}

// elementwise: dt (bf16 deltas), gxm = [gamma_x | m]
__global__ __launch_bounds__(256) void k_elem(const float* __restrict__ deltas,
                                              const float* __restrict__ masks,
                                              const float* __restrict__ Wtdx,
                                              const float* __restrict__ btdx,
                                              unsigned char* wsb) {
    ushortT* dt  = (ushortT*)(wsb + OB_DT);
    ushortT* gxm = (ushortT*)(wsb + OB_GXM);
    int tid = threadIdx.x, lane = tid & 63;
    int row = blockIdx.x * 4 + (tid >> 6);              // 0..25599 (b-major)
    int f0 = lane * 4;
    float4 d = *(const float4*)(deltas + (size_t)row * 256 + f0);
    float4 m = *(const float4*)(masks + (size_t)row * 256 + f0);
    ushortT* pd = dt + (size_t)row * 256 + f0;
    pd[0] = f2bf(d.x); pd[1] = f2bf(d.y); pd[2] = f2bf(d.z); pd[3] = f2bf(d.w);
    float gx0 = expf(-fmaxf(d.x * Wtdx[(size_t)(f0 + 0) * 257] + btdx[f0 + 0], 0.f));
    float gx1 = expf(-fmaxf(d.y * Wtdx[(size_t)(f0 + 1) * 257] + btdx[f0 + 1], 0.f));
    float gx2 = expf(-fmaxf(d.z * Wtdx[(size_t)(f0 + 2) * 257] + btdx[f0 + 2], 0.f));
    float gx3 = expf(-fmaxf(d.w * Wtdx[(size_t)(f0 + 3) * 257] + btdx[f0 + 3], 0.f));
    ushortT* pg = gxm + (size_t)row * 512 + f0;
    pg[0] = f2bf(gx0); pg[1] = f2bf(gx1); pg[2] = f2bf(gx2); pg[3] = f2bf(gx3);
    ushortT* pm = gxm + (size_t)row * 512 + 256 + f0;
    pm[0] = f2bf(m.x); pm[1] = f2bf(m.y); pm[2] = f2bf(m.z); pm[3] = f2bf(m.w);
}

// gamma_h = exp(-relu(dt @ W_td_h^T + b)) -> TIME-major ght[t][b][512]
__global__ __launch_bounds__(256) void k_gemm_gh(const float* __restrict__ b_td_h,
                                                 unsigned char* wsb) {
    const ushortT* A  = (const ushortT*)(wsb + OB_DT);
    const ushortT* Bw = (const ushortT*)(wsb + OB_BTH);
    ushortT* ght = (ushortT*)(wsb + OB_GHT);
    int tid = threadIdx.x, wave = tid >> 6, lane = tid & 63, quad = lane >> 4, l16 = lane & 15;
    int mb = blockIdx.x * 64, nb = blockIdx.y * 64;
    int r0 = mb + wave * 16;
    f32x4 acc[4] = {};
    const ushortT* arow = A + (size_t)(r0 + l16) * 256 + quad * 8;
    const ushortT* brow = Bw + (size_t)(nb + l16) * 256 + quad * 8;
    for (int kc = 0; kc < 8; ++kc) {
        short8 a = *(const short8*)(arow + kc * 32);
#pragma unroll
        for (int nt = 0; nt < 4; ++nt) {
            short8 b = *(const short8*)(brow + (size_t)nt * 16 * 256 + kc * 32);
            acc[nt] = __builtin_amdgcn_mfma_f32_16x16x32_bf16(a, b, acc[nt], 0, 0, 0);
        }
    }
#pragma unroll
    for (int nt = 0; nt < 4; ++nt) {
        int n = nb + nt * 16 + l16;
        float bias = b_td_h[n];
#pragma unroll
        for (int r4 = 0; r4 < 4; ++r4) {
            int row = r0 + quad * 4 + r4;
            int bb = row / 100, tt = row - bb * 100;
            float v = acc[nt][r4] + bias;
            ght[((size_t)tt * 256 + bb) * 512 + n] = f2bf(expf(-fmaxf(v, 0.f)));
        }
    }
}

// alpha = sigmoid(gxm @ W_comb^T + b) -> TIME-major alt[t][b][256]
__global__ __launch_bounds__(256) void k_gemm_al(const float* __restrict__ b_comb,
                                                 unsigned char* wsb) {
    const ushortT* A  = (const ushortT*)(wsb + OB_GXM);
    const ushortT* Bw = (const ushortT*)(wsb + OB_BCB);
    ushortT* alt = (ushortT*)(wsb + OB_ALT);
    int tid = threadIdx.x, wave = tid >> 6, lane = tid & 63, quad = lane >> 4, l16 = lane & 15;
    int mb = blockIdx.x * 64, nb = blockIdx.y * 64;
    int r0 = mb + wave * 16;
    f32x4 acc[4] = {};
    const ushortT* arow = A + (size_t)(r0 + l16) * 512 + quad * 8;
    const ushortT* brow = Bw + (size_t)(nb + l16) * 512 + quad * 8;
    for (int kc = 0; kc < 16; ++kc) {
        short8 a = *(const short8*)(arow + kc * 32);
#pragma unroll
        for (int nt = 0; nt < 4; ++nt) {
            short8 b = *(const short8*)(brow + (size_t)nt * 16 * 512 + kc * 32);
            acc[nt] = __builtin_amdgcn_mfma_f32_16x16x32_bf16(a, b, acc[nt], 0, 0, 0);
        }
    }
#pragma unroll
    for (int nt = 0; nt < 4; ++nt) {
        int n = nb + nt * 16 + l16;
        float bias = b_comb[n];
#pragma unroll
        for (int r4 = 0; r4 < 4; ++r4) {
            int row = r0 + quad * 4 + r4;
            int bb = row / 100, tt = row - bb * 100;
            alt[((size_t)tt * 256 + bb) * 256 + n] = f2bf(sigm(acc[nt][r4] + bias));
        }
    }
}

__global__ __launch_bounds__(64) void k_zero(float* out) {
    if (threadIdx.x == 0) out[6684672] = 0.0f;   // loss slot (atomicAdd target)
}

// ---------------- persistent row-local kernel (16 wgs, zero grid sync) ----

__global__ __launch_bounds__(512, 1) void k_persist(const float* __restrict__ values,
                                                    const float* __restrict__ masks,
                                                    const float* __restrict__ b_hist,
                                                    const float* __restrict__ b_feat,
                                                    float* __restrict__ out,
                                                    unsigned char* __restrict__ wsb) {
    const float* den   = (const float*)(wsb + OB_DEN);
    const float* biasp = (const float*)(wsb + OB_BIASP);
    const ushortT* Ba  = (const ushortT*)(wsb + OB_BA);
    const ushortT* Bf  = (const ushortT*)(wsb + OB_BF);
    const ushortT* Bc  = (const ushortT*)(wsb + OB_BC);
    const ushortT* ght = (const ushortT*)(wsb + OB_GHT);
    const ushortT* alt = (const ushortT*)(wsb + OB_ALT);

    // A-slab per parity: row-major [16][1032(pad)] bf16, K layout =
    // [cc(0:256) | m(256:512) | hdec(512:1024)]
    __shared__ ushortT Aslab[2][16 * 1032];      // 66,048 B
    __shared__ ushortT xcs[16 * 264];            //  8,448 B  x_c bf16
    __shared__ float   cst[16 * 516];            // 33,024 B  LSTM c state
    __shared__ float   xhs[16 * 260];            // 16,640 B  x_h fp32
    __shared__ float   scr8[8][16 * 17 + 12];    //  9,088 B  per-wave transpose / loss red

    const int tid = threadIdx.x;
    const int wave = tid >> 6, lane = tid & 63, quad = lane >> 4, l16 = lane & 15;
    const int r0 = blockIdx.x * 16;              // this wg's 16 batch rows

    // init: hdec(t=0)=0, c=0
    for (int i = tid; i < 16 * 512; i += 512) {
        int rr = i >> 9, k = i & 511;
        Aslab[0][rr * 1032 + 512 + k] = 0;
    }
    for (int i = tid; i < 16 * 516; i += 512) cst[i] = 0.f;
    __syncthreads();

    float lacc = 0.f;

    for (int t = 0; t < T_; ++t) {
        const int p = t & 1;
        const float invd = 1.0f / (den[t] + 1e-9f);

        // stage m (bf16) -> Aslab[p] cols 256..511
        for (int i = tid; i < 1024; i += 512) {
            int rr = i >> 6, c4 = i & 63;
            float4 m4 = *(const float4*)(masks + ((size_t)(r0 + rr) * T_ + t) * 256 + c4 * 4);
            ushortT* dst = &Aslab[p][rr * 1032 + 256 + c4 * 4];
            dst[0] = f2bf(m4.x); dst[1] = f2bf(m4.y); dst[2] = f2bf(m4.z); dst[3] = f2bf(m4.w);
        }
        __syncthreads();   // barrier 1: orders C(t-1) hdec + stage-m before use

        // ---- phase A: x_h = hdec @ W_hist^T  [16,256], K=512 ----
#pragma unroll
        for (int s = 0; s < 2; ++s) {
            int n0 = (wave * 2 + s) * 16;
            f32x4 acc = {0.f, 0.f, 0.f, 0.f};
#pragma unroll 4
            for (int kc = 0; kc < 16; ++kc) {
                short8 a = *(const short8*)&Aslab[p][l16 * 1032 + 512 + kc * 32 + quad * 8];
                short8 b = *(const short8*)(Ba + (size_t)(n0 + l16) * 512 + kc * 32 + quad * 8);
                acc = __builtin_amdgcn_mfma_f32_16x16x32_bf16(a, b, acc, 0, 0, 0);
            }
            int n = n0 + l16;
            float bh = b_hist[n];
#pragma unroll
            for (int r4 = 0; r4 < 4; ++r4) {
                int rr = quad * 4 + r4, b_ = r0 + rr;
                float v = acc[r4] + bh;
                size_t idx = ((size_t)b_ * T_ + t) * 256 + n;
                float x = values[idx], m = masks[idx];
                xhs[rr * 260 + n] = v;
                xcs[rr * 264 + n] = f2bf(v + m * (x - v));
                lacc += fabsf(v - x) * m * invd;
            }
        }
        __syncthreads();   // barrier 2

        // ---- phase B: z_h = x_c @ Wf^T; c_h, c_c, imputed ----
#pragma unroll
        for (int s = 0; s < 2; ++s) {
            int n0 = (wave * 2 + s) * 16;
            f32x4 acc = {0.f, 0.f, 0.f, 0.f};
#pragma unroll 4
            for (int kc = 0; kc < 8; ++kc) {
                short8 a = *(const short8*)&xcs[l16 * 264 + kc * 32 + quad * 8];
                short8 b = *(const short8*)(Bf + (size_t)(n0 + l16) * 256 + kc * 32 + quad * 8);
                acc = __builtin_amdgcn_mfma_f32_16x16x32_bf16(a, b, acc, 0, 0, 0);
            }
            int n = n0 + l16;
            float bfv = b_feat[n];
#pragma unroll
            for (int r4 = 0; r4 < 4; ++r4) {
                int rr = quad * 4 + r4, b_ = r0 + rr;
                float z = fmaxf(acc[r4] + bfv, 0.f);
                float a_ = bf2f(alt[((size_t)t * 256 + b_) * 256 + n]);
                float xh = xhs[rr * 260 + n];
                float ch = xh + a_ * (z - xh);
                size_t idx = ((size_t)b_ * T_ + t) * 256 + n;
                float x = values[idx], m = masks[idx];
                float ccv = ch + m * (x - ch);
                out[idx] = ccv;                        // imputed[:,t,:] == c_c
                Aslab[p][rr * 1032 + n] = f2bf(ccv);   // cc region
                lacc += (fabsf(z - x) + fabsf(ch - x)) * m * invd;
            }
        }
        __syncthreads();   // barrier 3

        // ---- phase C: gates = [cc|m|hdec] @ Bc^T (K=1024) + fused LSTM ----
        // wave owns cols [wave*256, wave*256+256) = units [wave*64, +64)
        for (int nt = 0; nt < 16; nt += 2) {
            f32x4 a0 = {0.f, 0.f, 0.f, 0.f}, a1 = {0.f, 0.f, 0.f, 0.f};
            const ushortT* B0 = Bc + (size_t)(wave * 256 + nt * 16 + l16) * 1024 + quad * 8;
            const ushortT* B1 = B0 + (size_t)16 * 1024;
#pragma unroll 8
            for (int kc = 0; kc < 32; ++kc) {
                short8 a = *(const short8*)&Aslab[p][l16 * 1032 + kc * 32 + quad * 8];
                short8 b0 = *(const short8*)(B0 + kc * 32);
                short8 b1 = *(const short8*)(B1 + kc * 32);
                a0 = __builtin_amdgcn_mfma_f32_16x16x32_bf16(a, b0, a0, 0, 0, 0);
                a1 = __builtin_amdgcn_mfma_f32_16x16x32_bf16(a, b1, a1, 0, 0, 0);
            }
#pragma unroll
            for (int h = 0; h < 2; ++h) {
                f32x4 acc = h ? a1 : a0;
                int n = wave * 256 + (nt + h) * 16 + l16;
                float bp = biasp[n];
#pragma unroll
                for (int r4 = 0; r4 < 4; ++r4)
                    scr8[wave][(quad * 4 + r4) * 17 + l16] = acc[r4] + bp;
                int rloc = lane >> 2, u = lane & 3;
                float gi = scr8[wave][rloc * 17 + u * 4 + 0];
                float gf = scr8[wave][rloc * 17 + u * 4 + 1];
                float gg = scr8[wave][rloc * 17 + u * 4 + 2];
                float go = scr8[wave][rloc * 17 + u * 4 + 3];
                int b_ = r0 + rloc;
                int j = wave * 64 + (nt + h) * 4 + u;
                float c = cst[rloc * 516 + j];
                float cn = sigm(gf) * c + sigm(gi) * tanhf(gg);
                float hn = sigm(go) * tanhf(cn);
                cst[rloc * 516 + j] = cn;
                if (t < T_ - 1) {
                    float gv = bf2f(ght[((size_t)(t + 1) * 256 + b_) * 512 + j]);
                    Aslab[p ^ 1][rloc * 1032 + 512 + j] = f2bf(hn * gv);
                } else {
                    out[6553600 + (size_t)b_ * 512 + j] = hn;   // final h
                }
            }
        }
        // no barrier: barrier 1 of next step orders hdec-writes before reads
    }

    // ---- loss: block reduce, one device-scope atomicAdd per wg ----
    __syncthreads();
    float* redb = &scr8[0][0];
    redb[tid] = lacc;
    __syncthreads();
    for (int s = 256; s > 0; s >>= 1) {
        if (tid < s) redb[tid] += redb[tid + s];
        __syncthreads();
    }
    if (tid == 0) atomicAdd(out + 6684672, redb[0] / 300.0f);
}

extern "C" void kernel_launch(void* const* d_in, const int* in_sizes, int n_in,
                              void* d_out, int out_size, void* d_ws, size_t ws_size,
                              hipStream_t stream) {
    (void)in_sizes; (void)n_in; (void)out_size; (void)ws_size;
    const float* values = (const float*)d_in[0];
    const float* masks  = (const float*)d_in[1];
    const float* deltas = (const float*)d_in[2];
    const float* W_td_h = (const float*)d_in[3];
    const float* b_td_h = (const float*)d_in[4];
    const float* W_td_x = (const float*)d_in[5];
    const float* b_td_x = (const float*)d_in[6];
    const float* W_hist = (const float*)d_in[7];
    const float* b_hist = (const float*)d_in[8];
    const float* W_feat = (const float*)d_in[9];
    const float* b_feat = (const float*)d_in[10];
    const float* W_comb = (const float*)d_in[11];
    const float* b_comb = (const float*)d_in[12];
    const float* W_ih   = (const float*)d_in[13];
    const float* W_hh   = (const float*)d_in[14];
    const float* b_ih   = (const float*)d_in[15];
    const float* b_hh   = (const float*)d_in[16];

    unsigned char* wsb = (unsigned char*)d_ws;
    float* out = (float*)d_out;

    k_prepw<<<2048, 256, 0, stream>>>(W_ih, W_hh, b_ih, b_hh, W_hist, W_feat, W_comb, W_td_h, wsb);
    k_den<<<100, 256, 0, stream>>>(masks, wsb);
    k_elem<<<6400, 256, 0, stream>>>(deltas, masks, W_td_x, b_td_x, wsb);
    k_gemm_gh<<<dim3(400, 8), 256, 0, stream>>>(b_td_h, wsb);
    k_gemm_al<<<dim3(400, 4), 256, 0, stream>>>(b_comb, wsb);
    k_zero<<<1, 64, 0, stream>>>(out);
    k_persist<<<16, 512, 0, stream>>>(values, masks, b_hist, b_feat, out, wsb);
}